// Round 11
// baseline (88.788 us; speedup 1.0000x reference)
//
#include <hip/hip_runtime.h>
#include <math.h>

#define NQ    13
#define DIM   8192
#define BLOCK 1024
#define NGATE 26

// R11: occupancy attack. 1024 thr x 8 amps (16 VGPR state), 64KB LDS,
// __launch_bounds__(1024,8) -> target 2 blocks/CU = 8 waves/SIMD (2x R7).
// Gate split 13 = P1{i0,i1,i2 reg; i3,i4 dpp} + P2{i5 reg; i6..i9 dpp} +
// P3{i10 reg; i11,i12 dpp}. Maps verified bijective; bank quads balanced.
// Barrier/scatter discipline identical to R7 (4x-proven skeleton).

// Bank-quad spreading swizzle (GF(2)-linear): XOR addr[4:2] with addr[9:7].
__device__ __forceinline__ int SW(int a) { return a ^ (((a >> 7) & 7) << 2); }

// ---- CNOT-chain permutation (GF(2)-linear), compile-time ----
struct PCols { int c[NQ]; };
constexpr PCols make_cols(int r) {
    PCols P{};
    for (int b = 0; b < NQ; ++b) {
        int cc = 1 << b;
        for (int cq = 0; cq < NQ; ++cq) {
            const int cb = 12 - cq;
            const int tb = 12 - ((cq + r) % NQ);
            cc ^= ((cc >> cb) & 1) << tb;
        }
        P.c[b] = cc;
    }
    return P;
}
constexpr PCols C1 = make_cols(1);   // layer 0 CNOTs (r=1)
constexpr int make_rm6() {           // row 6 of layer-1 (r=2) permutation matrix
    int m = 0;
    for (int b = 0; b < NQ; ++b) m |= ((make_cols(2).c[b] >> 6) & 1) << b;
    return m;
}
constexpr int RM6 = make_rm6();

// scatter combos for P3 reg bits: j0->i0, j1->i1, j2->i10
struct Combos { int k[8]; };
constexpr Combos make_combos() {
    Combos K{};
    for (int j = 0; j < 8; ++j)
        K.k[j] = ((j & 1) ? C1.c[0] : 0) ^ ((j & 2) ? C1.c[1] : 0)
               ^ ((j & 4) ? C1.c[10] : 0);
    return K;
}
constexpr Combos KC = make_combos();

// per-j PauliZ sign parity (j bits -> i bits {0,1,10})
constexpr int make_sjw() {
    int wv = 0;
    for (int j = 0; j < 8; ++j) {
        const int jm = (j & 3) | (((j >> 2) & 1) << 10);
        wv |= (__builtin_popcount(jm & RM6) & 1) << j;
    }
    return wv;
}
constexpr int SJW = make_sjw();

// ---- float2 complex helpers (R7 scalar-fmaf form) ----
__device__ __forceinline__ float2 f2mul(float s, float2 a) {
    return make_float2(s * a.x, s * a.y);
}
__device__ __forceinline__ float2 f2fma(float s, float2 a, float2 b) {
    return make_float2(fmaf(s, a.x, b.x), fmaf(s, a.y, b.y));
}
__device__ __forceinline__ float2 fswap(float2 a) { return make_float2(-a.y, a.x); }

// gate matrix as two float4 broadcasts (LDS):
//   a = {u00r,u00i,u01r,u01i}, b = {u10r,u10i,u11r,u11i}
struct G8 { float4 a, b; };
__device__ __forceinline__ G8 ldg8(const float* gm, int gi) {
    G8 g;
    g.a = *(const float4*)&gm[gi * 8];
    g.b = *(const float4*)&gm[gi * 8 + 4];
    return g;
}

// Rot gate on 8-amp register subcube, pair bit = reg index bit P (P in 0..2)
template<int P>
__device__ __forceinline__ void rotp(float2* c, const G8 g) {
    #pragma unroll
    for (int m = 0; m < 4; ++m) {
        const int j0 = ((m >> P) << (P + 1)) | (m & ((1 << P) - 1));
        const int j1 = j0 | (1 << P);
        const float2 a0 = c[j0], a1 = c[j1];
        const float2 s0 = fswap(a0), s1 = fswap(a1);
        c[j0] = f2fma(g.a.w, s1, f2fma(g.a.z, a1, f2fma(g.a.y, s0, f2mul(g.a.x, a0))));
        c[j1] = f2fma(g.b.w, s1, f2fma(g.b.z, a1, f2fma(g.b.y, s0, f2mul(g.b.x, a0))));
    }
}

// DPP lane exchanges: xor1=quad[1,0,3,2]; xor2=quad[2,3,0,1];
// xor4 = half_mirror(^7) o quad_rev(^3); xor8 = mirror(^15) o half_mirror(^7).
// Chained forms correctness-proven in R5 (passed absmax 6.1e-5).
#define DPP_XOR1 0xB1
#define DPP_XOR2 0x4E
#define DPP_QREV 0x1B
#define DPP_HMIR 0x141
#define DPP_MIR  0x140

template<int CTRL>
__device__ __forceinline__ float dpp1(float v) {
    return __int_as_float(
        __builtin_amdgcn_update_dpp(0, __float_as_int(v), CTRL, 0xf, 0xf, true));
}
template<int CA, int CB>
__device__ __forceinline__ float dppx(float v) {
    float r = dpp1<CA>(v);
    if constexpr (CB >= 0) r = dpp1<CB>(r);
    return r;
}
template<int CA, int CB>
__device__ __forceinline__ void rotlane(float2* c, const G8 g, const bool hi) {
    const float Ar = hi ? g.b.z : g.a.x;
    const float Ai = hi ? g.b.w : g.a.y;
    const float Br = hi ? g.b.x : g.a.z;
    const float Bi = hi ? g.b.y : g.a.w;
    #pragma unroll
    for (int j = 0; j < 8; ++j) {
        const float2 p  = make_float2(dppx<CA, CB>(c[j].x), dppx<CA, CB>(c[j].y));
        const float2 so = fswap(c[j]), sp = fswap(p);
        c[j] = f2fma(Bi, sp, f2fma(Br, p, f2fma(Ai, so, f2mul(Ar, c[j]))));
    }
}

__device__ __forceinline__ void loadgrp(const float* re, const float* im, int a, float2* c) {
    const float4 r = *(const float4*)&re[a];
    const float4 i = *(const float4*)&im[a];
    c[0] = make_float2(r.x, i.x); c[1] = make_float2(r.y, i.y);
    c[2] = make_float2(r.z, i.z); c[3] = make_float2(r.w, i.w);
}
__device__ __forceinline__ void storegrp(float* re, float* im, int a, const float2* c) {
    *(float4*)&re[a] = make_float4(c[0].x, c[1].x, c[2].x, c[3].x);
    *(float4*)&im[a] = make_float4(c[0].y, c[1].y, c[2].y, c[3].y);
}

__global__ __launch_bounds__(BLOCK, 8) void qsim_kernel(
    const float* __restrict__ x,
    const float* __restrict__ w,
    float* __restrict__ out)
{
    __shared__ __align__(16) float re[DIM];
    __shared__ __align__(16) float im[DIM];
    __shared__ __align__(16) float gm[NGATE * 8];
    __shared__ float red_ss[16], red_acc[16];

    const int b = blockIdx.x;
    const int t = threadIdx.x;   // 10 bits

    // ---- gate matrices, 26 threads, once per block ----
    if (t < NGATE) {
        const float phi = w[t * 3 + 0], theta = w[t * 3 + 1], omega = w[t * 3 + 2];
        float co, si;  sincosf(0.5f * theta, &si, &co);
        float sps, cps, sds, cds;
        sincosf(0.5f * (phi + omega), &sps, &cps);
        sincosf(0.5f * (phi - omega), &sds, &cds);
        float* g = &gm[t * 8];
        g[0] =  cps * co;  g[1] = -sps * co;   // u00
        g[2] = -cds * si;  g[3] = -sds * si;   // u01
        g[4] =  cds * si;  g[5] = -sds * si;   // u10
        g[6] =  cps * co;  g[7] =  sps * co;   // u11
    }

    // ---- layer-0 state: global -> registers in P1 order (i = t<<3 | j) ----
    // im == 0 at entry (state is real). ||x||^2 folded into the same loads.
    const float4* x4 = (const float4*)(x + (size_t)b * DIM);
    float2 c[8];
    float ss = 0.f;
    #pragma unroll
    for (int g = 0; g < 2; ++g) {
        const float4 v = x4[(t << 1) | g];
        c[4 * g + 0] = make_float2(v.x, 0.f);
        c[4 * g + 1] = make_float2(v.y, 0.f);
        c[4 * g + 2] = make_float2(v.z, 0.f);
        c[4 * g + 3] = make_float2(v.w, 0.f);
        ss += v.x * v.x + v.y * v.y + v.z * v.z + v.w * v.w;
    }
    #pragma unroll
    for (int off = 32; off > 0; off >>= 1) ss += __shfl_down(ss, off, 64);
    if ((t & 63) == 0) red_ss[t >> 6] = ss;
    __syncthreads();                      // B1: gm + red_ss visible

    // Per-pass (t,j)->i maps (all bijective, verified bit-by-bit):
    //  P1: i = t<<3 | j.           reg i0,i1,i2 (j); dpp i3=t0(x1), i4=t1(x2)
    //  P2: i0,i1=j[1:0]; i2=t4; i3=t5; i4=t6; i5=j2; i6=t0; i7=t1; i8=t2;
    //      i9=t3; i10=t7; i11=t8; i12=t9.  reg i5; dpp i6(x1),i7(x2),i8(x4),i9(x8)
    //  P3: i0,i1=j[1:0]; i[9:2]=t[9:2]; i10=j2; i11=t0; i12=t1.
    //      reg i10; dpp i11(x1), i12(x2)
    const int base2 = (((t >> 4) & 1) << 2) | (((t >> 5) & 1) << 3)
                    | (((t >> 6) & 1) << 4) | ((t & 1) << 6)
                    | (((t >> 1) & 1) << 7) | (((t >> 2) & 1) << 8)
                    | (((t >> 3) & 1) << 9) | (((t >> 7) & 1) << 10)
                    | (((t >> 8) & 1) << 11) | (((t >> 9) & 1) << 12);
    const int base3 = (((t >> 2) & 255) << 2) | ((t & 1) << 11) | (((t >> 1) & 1) << 12);

    #pragma unroll
    for (int l = 0; l < 2; ++l) {
        const int G = l * 13;

        // ---- pass 1: 5 gates (bits 0,1,2 reg; 3,4 dpp) ----
        if (l != 0) {
            #pragma unroll
            for (int g = 0; g < 2; ++g)
                loadgrp(re, im, SW((t << 3) | (g << 2)), &c[4 * g]);
        }
        rotp<0>(c, ldg8(gm, G + 12));
        rotp<1>(c, ldg8(gm, G + 11));
        rotp<2>(c, ldg8(gm, G + 10));
        rotlane<DPP_XOR1, -1>(c, ldg8(gm, G + 9), (t & 1) != 0);
        rotlane<DPP_XOR2, -1>(c, ldg8(gm, G + 8), (t & 2) != 0);
        #pragma unroll
        for (int g = 0; g < 2; ++g)
            storegrp(re, im, SW((t << 3) | (g << 2)), &c[4 * g]);
        __syncthreads();

        // ---- pass 2: 5 gates (bit 5 reg; 6,7,8,9 dpp) ----
        #pragma unroll
        for (int g = 0; g < 2; ++g)
            loadgrp(re, im, SW(base2 | (g << 5)), &c[4 * g]);
        rotp<2>(c, ldg8(gm, G + 7));
        rotlane<DPP_XOR1, -1>(c, ldg8(gm, G + 6), (t & 1) != 0);
        rotlane<DPP_XOR2, -1>(c, ldg8(gm, G + 5), (t & 2) != 0);
        rotlane<DPP_HMIR, DPP_QREV>(c, ldg8(gm, G + 4), (t & 4) != 0);
        rotlane<DPP_MIR,  DPP_HMIR>(c, ldg8(gm, G + 3), (t & 8) != 0);
        #pragma unroll
        for (int g = 0; g < 2; ++g)
            storegrp(re, im, SW(base2 | (g << 5)), &c[4 * g]);
        __syncthreads();

        // ---- pass 3: 3 gates (bit 10 reg; 11,12 dpp) ----
        #pragma unroll
        for (int g = 0; g < 2; ++g)
            loadgrp(re, im, SW(base3 | (g << 10)), &c[4 * g]);
        if (l == 0) __syncthreads();   // reads drained before scatter (layer 0 only)
        rotp<2>(c, ldg8(gm, G + 2));
        rotlane<DPP_XOR1, -1>(c, ldg8(gm, G + 1), (t & 1) != 0);
        rotlane<DPP_XOR2, -1>(c, ldg8(gm, G + 0), (t & 2) != 0);

        if (l == 0) {
            // all 13 layer-0 CNOTs as one GF(2)-linear scatter
            // t-bit -> C1 column per the P3 map: t0->c11, t1->c12, t[9:2]->c[9:2]
            int mb = 0;
            if (t & 1) mb ^= C1.c[11];
            if (t & 2) mb ^= C1.c[12];
            #pragma unroll
            for (int bb = 0; bb < 8; ++bb)
                if ((t >> (bb + 2)) & 1) mb ^= C1.c[2 + bb];
            #pragma unroll
            for (int j = 0; j < 8; ++j) {
                const int a = SW(mb ^ KC.k[j]);
                re[a] = c[j].x; im[a] = c[j].y;
            }
            __syncthreads();
        }
    }

    // ---- layer-1 CNOTs + PauliZ(q6) folded: sign = popc(i & RM6) & 1 ----
    const int sbase = __popc(base3 & RM6) & 1;   // base3 == thread's fixed i-bits
    float acc = 0.f;
    #pragma unroll
    for (int j = 0; j < 8; ++j) {
        const float p = c[j].x * c[j].x + c[j].y * c[j].y;
        acc += (sbase ^ ((SJW >> j) & 1)) ? -p : p;
    }
    #pragma unroll
    for (int off = 32; off > 0; off >>= 1) acc += __shfl_down(acc, off, 64);
    if ((t & 63) == 0) red_acc[t >> 6] = acc;
    __syncthreads();
    if (t == 0) {
        float ta = 0.f, ts = 0.f;
        #pragma unroll
        for (int i = 0; i < 16; ++i) { ta += red_acc[i]; ts += red_ss[i]; }
        out[b] = ta / ts;
    }
}

extern "C" void kernel_launch(void* const* d_in, const int* in_sizes, int n_in,
                              void* d_out, int out_size, void* d_ws, size_t ws_size,
                              hipStream_t stream) {
    const float* x = (const float*)d_in[0];   // (512, 8192) fp32
    const float* w = (const float*)d_in[1];   // (2, 13, 3) fp32
    float* out = (float*)d_out;               // (512,) fp32
    const int B = in_sizes[0] / DIM;
    qsim_kernel<<<B, BLOCK, 0, stream>>>(x, w, out);
}

// Round 12
// 84.365 us; speedup vs baseline: 1.0524x; 1.0524x over previous
//
#include <hip/hip_runtime.h>
#include <math.h>

#define NQ    13
#define DIM   8192
#define BLOCK 512
#define NGATE 26

// R12 = R7 champion restored byte-for-byte (84.4 us, passed, absmax 6.1e-5).
//  - 512 threads x 16 amps, separate re/im LDS arrays, 3 passes/layer {6,4,3}
//  - gate matrices in LDS, read as 2x b128 broadcast per gate
//  - layer-0 im elision (state starts real)
//  - layer-0 CNOT chain folded into one GF(2)-linear scatter
//  - layer-1 CNOT chain + PauliZ(q6) folded into the final reduce sign
// Failed lines (do not retry): v2f/packed math (R8/R9 +9us), global gate
// buffer (R8), 2-pass remaps (R5 -8us), chained-DPP gates (R5/R11),
// 1024-thread blocks (R11 -4us), P0 elision via strided global load (R10).

// Bank-quad spreading swizzle: XOR addr[4:2] with addr[9:7]. Preserves
// addr[1:0] => b128 groups stay intact. Applied at every LDS access.
__device__ __forceinline__ int SW(int a) { return a ^ (((a >> 7) & 7) << 2); }

// ---- CNOT-chain permutation (GF(2)-linear), compile-time ----
struct PCols { int c[NQ]; };
constexpr PCols make_cols(int r) {
    PCols P{};
    for (int b = 0; b < NQ; ++b) {
        int cc = 1 << b;
        for (int cq = 0; cq < NQ; ++cq) {
            const int cb = 12 - cq;
            const int tb = 12 - ((cq + r) % NQ);
            cc ^= ((cc >> cb) & 1) << tb;
        }
        P.c[b] = cc;
    }
    return P;
}
constexpr PCols C1 = make_cols(1);   // layer 0 CNOTs (r=1)
constexpr int make_rm6() {           // row 6 of layer-1 (r=2) permutation matrix
    int m = 0;
    for (int b = 0; b < NQ; ++b) m |= ((make_cols(2).c[b] >> 6) & 1) << b;
    return m;
}
constexpr int RM6 = make_rm6();

// scatter combos for pass-3 reg bits: j0->i0, j1->i1, j2->i10, j3->i11
struct Combos { int k[16]; };
constexpr Combos make_combos() {
    Combos K{};
    for (int j = 0; j < 16; ++j)
        K.k[j] = ((j & 1) ? C1.c[0] : 0) ^ ((j & 2) ? C1.c[1] : 0)
               ^ ((j & 4) ? C1.c[10] : 0) ^ ((j & 8) ? C1.c[11] : 0);
    return K;
}
constexpr Combos KC = make_combos();

// per-j PauliZ sign parity for the final reduce (j bits -> i bits {0,1,10,11})
constexpr int make_sjw() {
    int wv = 0;
    for (int j = 0; j < 16; ++j) {
        const int jm = (j & 3) | (((j >> 2) & 3) << 10);
        wv |= (__builtin_popcount(jm & RM6) & 1) << j;
    }
    return wv;
}
constexpr int SJW = make_sjw();

// ---- float2 complex helpers ----
__device__ __forceinline__ float2 f2mul(float s, float2 a) {
    return make_float2(s * a.x, s * a.y);
}
__device__ __forceinline__ float2 f2fma(float s, float2 a, float2 b) {
    return make_float2(fmaf(s, a.x, b.x), fmaf(s, a.y, b.y));
}
__device__ __forceinline__ float2 fswap(float2 a) { return make_float2(-a.y, a.x); }

// gate matrix as two float4 broadcasts:
//   a = {u00r,u00i,u01r,u01i}, b = {u10r,u10i,u11r,u11i}
struct G8 { float4 a, b; };
__device__ __forceinline__ G8 ldg8(const float* gm, int gi) {
    G8 g;
    g.a = *(const float4*)&gm[gi * 8];
    g.b = *(const float4*)&gm[gi * 8 + 4];
    return g;
}

// Rot gate on 16-amp register subcube, pair bit = reg index bit P
template<int P>
__device__ __forceinline__ void rotp(float2* c, const G8 g) {
    #pragma unroll
    for (int m = 0; m < 8; ++m) {
        const int j0 = ((m >> P) << (P + 1)) | (m & ((1 << P) - 1));
        const int j1 = j0 | (1 << P);
        const float2 a0 = c[j0], a1 = c[j1];
        const float2 s0 = fswap(a0), s1 = fswap(a1);
        c[j0] = f2fma(g.a.w, s1, f2fma(g.a.z, a1, f2fma(g.a.y, s0, f2mul(g.a.x, a0))));
        c[j1] = f2fma(g.b.w, s1, f2fma(g.b.z, a1, f2fma(g.b.y, s0, f2mul(g.b.x, a0))));
    }
}

// DPP quad-perm lane exchange: 0xB1 -> lane^1, 0x4E -> lane^2
template<int CTRL>
__device__ __forceinline__ float dppx(float v) {
    return __int_as_float(
        __builtin_amdgcn_update_dpp(0, __float_as_int(v), CTRL, 0xf, 0xf, true));
}
template<int CTRL>
__device__ __forceinline__ void rotlane(float2* c, const G8 g, const bool hi) {
    const float Ar = hi ? g.b.z : g.a.x;
    const float Ai = hi ? g.b.w : g.a.y;
    const float Br = hi ? g.b.x : g.a.z;
    const float Bi = hi ? g.b.y : g.a.w;
    #pragma unroll
    for (int j = 0; j < 16; ++j) {
        const float2 p  = make_float2(dppx<CTRL>(c[j].x), dppx<CTRL>(c[j].y));
        const float2 so = fswap(c[j]), sp = fswap(p);
        c[j] = f2fma(Bi, sp, f2fma(Br, p, f2fma(Ai, so, f2mul(Ar, c[j]))));
    }
}

__device__ __forceinline__ void loadgrp(const float* re, const float* im, int a, float2* c) {
    const float4 r = *(const float4*)&re[a];
    const float4 i = *(const float4*)&im[a];
    c[0] = make_float2(r.x, i.x); c[1] = make_float2(r.y, i.y);
    c[2] = make_float2(r.z, i.z); c[3] = make_float2(r.w, i.w);
}
__device__ __forceinline__ void storegrp(float* re, float* im, int a, const float2* c) {
    *(float4*)&re[a] = make_float4(c[0].x, c[1].x, c[2].x, c[3].x);
    *(float4*)&im[a] = make_float4(c[0].y, c[1].y, c[2].y, c[3].y);
}

__global__ __launch_bounds__(BLOCK, 4) void qsim_kernel(
    const float* __restrict__ x,
    const float* __restrict__ w,
    float* __restrict__ out)
{
    __shared__ __align__(16) float re[DIM];
    __shared__ __align__(16) float im[DIM];
    __shared__ __align__(16) float gm[NGATE * 8];
    __shared__ float red_ss[8], red_acc[8];

    const int b = blockIdx.x;
    const int t = threadIdx.x;

    // ---- gate matrices, 26 threads, once per block ----
    if (t < NGATE) {
        const float phi = w[t * 3 + 0], theta = w[t * 3 + 1], omega = w[t * 3 + 2];
        float co, si;  sincosf(0.5f * theta, &si, &co);
        float sps, cps, sds, cds;
        sincosf(0.5f * (phi + omega), &sps, &cps);
        sincosf(0.5f * (phi - omega), &sds, &cds);
        float* g = &gm[t * 8];
        g[0] =  cps * co;  g[1] = -sps * co;   // u00
        g[2] = -cds * si;  g[3] = -sds * si;   // u01
        g[4] =  cds * si;  g[5] = -sds * si;   // u10
        g[6] =  cps * co;  g[7] =  sps * co;   // u11
    }

    // ---- P0: coalesced global -> LDS (re only; state starts real), ss ----
    const float4* x4 = (const float4*)(x + (size_t)b * DIM);
    float ss = 0.f;
    #pragma unroll
    for (int k = 0; k < 4; ++k) {
        const int m = t + BLOCK * k;
        const int a = SW(4 * m);
        const float4 v = x4[m];
        *(float4*)&re[a] = v;
        ss += v.x * v.x + v.y * v.y + v.z * v.z + v.w * v.w;
    }
    #pragma unroll
    for (int off = 32; off > 0; off >>= 1) ss += __shfl_down(ss, off, 64);
    if ((t & 63) == 0) red_ss[t >> 6] = ss;
    __syncthreads();                      // B1: gm + re staging + red_ss visible
    float total = 0.f;
    #pragma unroll
    for (int i = 0; i < 8; ++i) total += red_ss[i];  // ||x||^2, invariant

    float2 c[16];

    // Per-pass (t,j)->i mappings (identical to R4/R7; all in-place, all b128):
    //  P1: i = t<<4 | j            reg i[3:0] (q12..q9), dpp i[5:4]=t[1:0] (q8,q7)
    //  P2: i[1:0]=j[1:0], i[7:6]=j[3:2], i[5:2]=t[5:2], i[9:8]=t[1:0], i[12:10]=t[8:6]
    //      reg gates i6,i7 (q6,q5), dpp i8,i9 (q4,q3)
    //  P3: i[1:0]=j[1:0], i[11:10]=j[3:2], i[9:2]=t[8:1], i12=t[0]
    //      reg gates i10,i11 (q2,q1), dpp i12 (q0)
    const int base2 = (((t >> 2) & 15) << 2) | ((t & 3) << 8) | (((t >> 6) & 7) << 10);
    const int base3 = (((t >> 1) & 255) << 2) | ((t & 1) << 12);

    #pragma unroll
    for (int l = 0; l < 2; ++l) {
        const int G = l * 13;

        // ---- pass 1: 6 gates (q12..q7) ----
        if (l == 0) {
            // im is identically zero at entry: load re only
            #pragma unroll
            for (int g = 0; g < 4; ++g) {
                const float4 r = *(const float4*)&re[SW((t << 4) | (g << 2))];
                c[4 * g + 0] = make_float2(r.x, 0.f);
                c[4 * g + 1] = make_float2(r.y, 0.f);
                c[4 * g + 2] = make_float2(r.z, 0.f);
                c[4 * g + 3] = make_float2(r.w, 0.f);
            }
        } else {
            #pragma unroll
            for (int g = 0; g < 4; ++g)
                loadgrp(re, im, SW((t << 4) | (g << 2)), &c[4 * g]);
        }
        rotp<0>(c, ldg8(gm, G + 12));
        rotp<1>(c, ldg8(gm, G + 11));
        rotp<2>(c, ldg8(gm, G + 10));
        rotp<3>(c, ldg8(gm, G +  9));
        rotlane<0xB1>(c, ldg8(gm, G + 8), (t & 1) != 0);
        rotlane<0x4E>(c, ldg8(gm, G + 7), (t & 2) != 0);
        #pragma unroll
        for (int g = 0; g < 4; ++g)
            storegrp(re, im, SW((t << 4) | (g << 2)), &c[4 * g]);
        __syncthreads();

        // ---- pass 2: 4 gates (q6..q3) ----
        #pragma unroll
        for (int h = 0; h < 4; ++h) loadgrp(re, im, SW(base2 | (h << 6)), &c[4 * h]);
        rotp<2>(c, ldg8(gm, G + 6));
        rotp<3>(c, ldg8(gm, G + 5));
        rotlane<0xB1>(c, ldg8(gm, G + 4), (t & 1) != 0);
        rotlane<0x4E>(c, ldg8(gm, G + 3), (t & 2) != 0);
        #pragma unroll
        for (int h = 0; h < 4; ++h) storegrp(re, im, SW(base2 | (h << 6)), &c[4 * h]);
        __syncthreads();

        // ---- pass 3: 3 gates (q2,q1,q0) ----
        #pragma unroll
        for (int h = 0; h < 4; ++h) loadgrp(re, im, SW(base3 | (h << 10)), &c[4 * h]);
        if (l == 0) __syncthreads();   // reads drained before scatter (layer 0 only)
        rotp<2>(c, ldg8(gm, G + 2));
        rotp<3>(c, ldg8(gm, G + 1));
        rotlane<0xB1>(c, ldg8(gm, G + 0), (t & 1) != 0);

        if (l == 0) {
            // all 13 layer-0 CNOTs as one GF(2)-linear scatter
            int mb = 0;
            if (t & 1) mb ^= C1.c[12];
            #pragma unroll
            for (int bb = 0; bb < 8; ++bb)
                if ((t >> (bb + 1)) & 1) mb ^= C1.c[2 + bb];
            #pragma unroll
            for (int j = 0; j < 16; ++j) {
                const int a = SW(mb ^ KC.k[j]);
                re[a] = c[j].x; im[a] = c[j].y;
            }
            __syncthreads();
        }
    }

    // ---- layer-1 CNOTs + PauliZ(q6) folded: sign = popc(i & RM6) & 1 ----
    const int sbase = __popc(base3 & RM6) & 1;   // base3 == thread's fixed i-bits
    float acc = 0.f;
    #pragma unroll
    for (int j = 0; j < 16; ++j) {
        const float p = c[j].x * c[j].x + c[j].y * c[j].y;
        acc += (sbase ^ ((SJW >> j) & 1)) ? -p : p;
    }
    #pragma unroll
    for (int off = 32; off > 0; off >>= 1) acc += __shfl_down(acc, off, 64);
    if ((t & 63) == 0) red_acc[t >> 6] = acc;
    __syncthreads();
    if (t == 0) {
        float tot = 0.f;
        #pragma unroll
        for (int i = 0; i < 8; ++i) tot += red_acc[i];
        out[b] = tot / total;
    }
}

extern "C" void kernel_launch(void* const* d_in, const int* in_sizes, int n_in,
                              void* d_out, int out_size, void* d_ws, size_t ws_size,
                              hipStream_t stream) {
    const float* x = (const float*)d_in[0];   // (512, 8192) fp32
    const float* w = (const float*)d_in[1];   // (2, 13, 3) fp32
    float* out = (float*)d_out;               // (512,) fp32
    const int B = in_sizes[0] / DIM;
    qsim_kernel<<<B, BLOCK, 0, stream>>>(x, w, out);
}